// Round 2
// baseline (1234.928 us; speedup 1.0000x reference)
//
#include <hip/hip_runtime.h>
#include <stdint.h>

#define NTOK 343
#define SCALE 0.17677669529663687f

// may_alias: all 32-bit type-punned accesses go through this (TBAA-safe).
typedef uint32_t u32a __attribute__((may_alias));

static __device__ __forceinline__ uint16_t f2bf(float f) {
    uint32_t u = __float_as_uint(f);
    u += 0x7fffu + ((u >> 16) & 1u);
    return (uint16_t)(u >> 16);
}
static __device__ __forceinline__ float bflo(uint32_t p) { return __uint_as_float(p << 16); }
static __device__ __forceinline__ float bfhi(uint32_t p) { return __uint_as_float(p & 0xffff0000u); }

#if __has_builtin(__builtin_amdgcn_fdot2_f32_bf16)
typedef __bf16 bf16x2_t __attribute__((ext_vector_type(2)));
static __device__ __forceinline__ float dot2bf(uint32_t a, uint32_t b, float c) {
    union { uint32_t u; bf16x2_t v; } ua, ub;
    ua.u = a; ub.u = b;
    return __builtin_amdgcn_fdot2_f32_bf16(ua.v, ub.v, c, false);
}
#else
static __device__ __forceinline__ float dot2bf(uint32_t a, uint32_t b, float c) {
    c = fmaf(bflo(a), bflo(b), c);
    c = fmaf(bfhi(a), bfhi(b), c);
    return c;
}
#endif

// K0: bias_l[h][i][j] = rpb_table[rel_index[i][j]][h]
__global__ __launch_bounds__(256) void bias_pre(const float* __restrict__ rpb,
                                                const int* __restrict__ rel,
                                                float* __restrict__ bias_l) {
    int e = blockIdx.x * 256 + threadIdx.x;
    const int total = 3 * NTOK * NTOK;
    if (e >= total) return;
    int h = e / (NTOK * NTOK);
    int ij = e % (NTOK * NTOK);
    bias_l[e] = rpb[rel[ij] * 3 + h];
}

// K1: qkv projection, fp32 compute, bf16 store. One block = (b, 64-token tile),
// loops over the 3 chunks (q rows 0..95, k rows 96..191, v rows 192..287).
__global__ __launch_bounds__(256) void qkv_kernel(
    const float* __restrict__ x, const float* __restrict__ qkv_w,
    const float* __restrict__ qkv_b,
    uint16_t* __restrict__ q_ws, uint16_t* __restrict__ k_ws, uint16_t* __restrict__ v_ws)
{
    __shared__ float x_t[64 * 96];     // [n_local][k]
    __shared__ float w_t[96 * 98];     // [k][c] padded stride 98
    const int b = blockIdx.x / 6;
    const int n0 = (blockIdx.x % 6) * 64;
    const int tid = threadIdx.x;

    for (int e = tid; e < 64 * 96; e += 256) {
        int n = n0 + (e / 96);
        x_t[e] = (n < NTOK) ? x[(size_t)(b * NTOK + n) * 96 + (e % 96)] : 0.f;
    }

    const int tc = tid & 15, tn = tid >> 4;
    const int cb = tc * 6, nb = tn * 4;

    for (int chunk = 0; chunk < 3; ++chunk) {
        __syncthreads();
        for (int e = tid; e < 96 * 96; e += 256) {
            int c = e / 96, k = e % 96;
            w_t[k * 98 + c] = qkv_w[(size_t)(chunk * 96 + c) * 96 + k];
        }
        __syncthreads();

        float acc[4][6];
        #pragma unroll
        for (int i = 0; i < 4; ++i)
            #pragma unroll
            for (int u = 0; u < 6; ++u) acc[i][u] = 0.f;

        #pragma unroll 4
        for (int k = 0; k < 96; ++k) {
            float xr[4], wr[6];
            #pragma unroll
            for (int i = 0; i < 4; ++i) xr[i] = x_t[(nb + i) * 96 + k];
            #pragma unroll
            for (int u = 0; u < 6; ++u) wr[u] = w_t[k * 98 + cb + u];
            #pragma unroll
            for (int i = 0; i < 4; ++i)
                #pragma unroll
                for (int u = 0; u < 6; ++u)
                    acc[i][u] = fmaf(xr[i], wr[u], acc[i][u]);
        }

        const float scl = (chunk == 0) ? SCALE : 1.f;
        uint16_t* dst = (chunk == 0) ? q_ws : ((chunk == 1) ? k_ws : v_ws);
        #pragma unroll
        for (int i = 0; i < 4; ++i) {
            int n = n0 + nb + i;
            if (n < NTOK) {
                #pragma unroll
                for (int u = 0; u < 6; u += 2) {
                    int c = cb + u;
                    int hh = c >> 5, dd = c & 31;   // pair never crosses a head boundary
                    float v0 = (acc[i][u]     + qkv_b[chunk * 96 + c])     * scl;
                    float v1 = (acc[i][u + 1] + qkv_b[chunk * 96 + c + 1]) * scl;
                    uint32_t pk = (uint32_t)f2bf(v0) | ((uint32_t)f2bf(v1) << 16);
                    *(u32a*)&dst[(size_t)((b * 3 + hh) * NTOK + n) * 32 + dd] = pk;
                }
            }
        }
    }
}

// K2: attention per (b,h). k,v staged in LDS (bf16), wave-per-row softmax,
// writes attnout rows into d_out (channel = h*32+d).
__global__ __launch_bounds__(512) void attn_kernel(
    const uint16_t* __restrict__ q_ws, const uint16_t* __restrict__ k_ws,
    const uint16_t* __restrict__ v_ws, const float* __restrict__ mask,
    const float* __restrict__ bias_l, float* __restrict__ out_attn)
{
    __shared__ uint32_t k_l[NTOK * 17];    // [n][dp] padded 17 dwords (coprime 32)
    __shared__ uint16_t vT[32 * 346];      // [d][n] padded 346 shorts (=173 dwords)
    __shared__ uint16_t p_buf[8][344];     // per-wave probabilities (bf16)

    const int bh = blockIdx.x;
    const int b = bh / 3, h = bh % 3, w = b & 63;
    const int tid = threadIdx.x, lane = tid & 63, wv = tid >> 6;

    const u32a* ksrc = (const u32a*)(k_ws + (size_t)bh * NTOK * 32);
    const u32a* vsrc = (const u32a*)(v_ws + (size_t)bh * NTOK * 32);
    for (int e = tid; e < NTOK * 16; e += 512) {
        int n = e >> 4, dp = e & 15;
        k_l[n * 17 + dp] = ksrc[e];
        uint32_t vv = vsrc[e];
        vT[(2 * dp) * 346 + n]     = (uint16_t)(vv & 0xffffu);
        vT[(2 * dp + 1) * 346 + n] = (uint16_t)(vv >> 16);
    }
    if (tid < 32) vT[tid * 346 + 343] = 0;   // zero pad column (paired PV read)
    __syncthreads();

    const u32a* qbase = (const u32a*)(q_ws + (size_t)bh * NTOK * 32);
    const float* maskw = mask + (size_t)w * NTOK * NTOK;
    const float* biash = bias_l + (size_t)h * NTOK * NTOK;

    for (int i = wv; i < NTOK; i += 8) {
        uint32_t qd[16];
        const u32a* qp = qbase + i * 16;
        #pragma unroll
        for (int dp = 0; dp < 16; ++dp) qd[dp] = qp[dp];

        const float* mi = maskw + (size_t)i * NTOK;
        const float* bi = biash + (size_t)i * NTOK;

        float s[6];
        #pragma unroll
        for (int t = 0; t < 6; ++t) {
            int j = t * 64 + lane;
            float a = -1e30f;
            if (t < 5 || lane < 23) {
                const uint32_t* kj = &k_l[j * 17];
                float acc = 0.f;
                #pragma unroll
                for (int dp = 0; dp < 16; ++dp) acc = dot2bf(qd[dp], kj[dp], acc);
                a = acc + bi[j] + mi[j];
            }
            s[t] = a;
        }

        float m = fmaxf(fmaxf(fmaxf(s[0], s[1]), fmaxf(s[2], s[3])), fmaxf(s[4], s[5]));
        #pragma unroll
        for (int off = 32; off >= 1; off >>= 1) m = fmaxf(m, __shfl_xor(m, off));
        float sum = 0.f;
        #pragma unroll
        for (int t = 0; t < 6; ++t) { s[t] = __expf(s[t] - m); sum += s[t]; }
        #pragma unroll
        for (int off = 32; off >= 1; off >>= 1) sum += __shfl_xor(sum, off);
        const float inv = 1.f / sum;

        #pragma unroll
        for (int t = 0; t < 6; ++t) {
            int j = t * 64 + lane;
            if (j < NTOK) p_buf[wv][j] = f2bf(s[t] * inv);
            else if (j == NTOK) p_buf[wv][343] = 0;
        }
        // Same-wave LDS RAW: HW DS pipeline is in-order per wave. Fence the
        // compiler (no reorder across) and drain lgkm before the PV reads.
        __asm__ __volatile__("" ::: "memory");
        __builtin_amdgcn_s_waitcnt(0xC07F);   // lgkmcnt(0)
        __asm__ __volatile__("" ::: "memory");

        const int d = lane & 31, half = lane >> 5;
        const int j0 = half ? 172 : 0;
        const int j1 = half ? 344 : 172;
        float acc = 0.f;
        const uint16_t* vd = &vT[d * 346];
        const uint16_t* pw = &p_buf[wv][0];
        #pragma unroll 4
        for (int j = j0; j < j1; j += 2) {
            uint32_t pp = *(const u32a*)&pw[j];
            uint32_t vv = *(const u32a*)&vd[j];
            acc = dot2bf(pp, vv, acc);
        }
        acc += __shfl_down(acc, 32);
        if (half == 0)
            out_attn[((size_t)b * NTOK + i) * 96 + h * 32 + d] = acc;
    }
}

// K3: output projection, in-place on d_out (row-local: stage -> barrier -> overwrite)
__global__ __launch_bounds__(256) void proj_kernel(
    const float* __restrict__ proj_w, const float* __restrict__ proj_b,
    float* __restrict__ out)
{
    __shared__ float a_t[64 * 96];
    __shared__ float w_t[96 * 98];
    const int r0 = blockIdx.x * 64;
    const int tid = threadIdx.x;
    for (int e = tid; e < 64 * 96; e += 256) a_t[e] = out[(size_t)r0 * 96 + e];
    for (int e = tid; e < 96 * 96; e += 256) {
        int c = e / 96, k = e % 96;
        w_t[k * 98 + c] = proj_w[(size_t)c * 96 + k];
    }
    __syncthreads();

    const int tc = tid & 15, tn = tid >> 4;
    const int cb = tc * 6, nb = tn * 4;
    float acc[4][6];
    #pragma unroll
    for (int i = 0; i < 4; ++i)
        #pragma unroll
        for (int u = 0; u < 6; ++u) acc[i][u] = 0.f;

    #pragma unroll 4
    for (int k = 0; k < 96; ++k) {
        float xr[4], wr[6];
        #pragma unroll
        for (int i = 0; i < 4; ++i) xr[i] = a_t[(nb + i) * 96 + k];
        #pragma unroll
        for (int u = 0; u < 6; ++u) wr[u] = w_t[k * 98 + cb + u];
        #pragma unroll
        for (int i = 0; i < 4; ++i)
            #pragma unroll
            for (int u = 0; u < 6; ++u)
                acc[i][u] = fmaf(xr[i], wr[u], acc[i][u]);
    }

    #pragma unroll
    for (int i = 0; i < 4; ++i) {
        int r = r0 + nb + i;
        #pragma unroll
        for (int u = 0; u < 6; ++u)
            out[(size_t)r * 96 + cb + u] = acc[i][u] + proj_b[cb + u];
    }
}

extern "C" void kernel_launch(void* const* d_in, const int* in_sizes, int n_in,
                              void* d_out, int out_size, void* d_ws, size_t ws_size,
                              hipStream_t stream) {
    const float* x      = (const float*)d_in[0];
    const float* mask   = (const float*)d_in[1];
    const float* qkv_w  = (const float*)d_in[2];
    const float* qkv_b  = (const float*)d_in[3];
    const float* proj_w = (const float*)d_in[4];
    const float* proj_b = (const float*)d_in[5];
    const float* rpb    = (const float*)d_in[6];
    const int*   rel    = (const int*)d_in[7];
    float* out = (float*)d_out;

    // ws layout: q,k,v bf16 [512*3][343][32] (33.7 MB each), then bias table (1.4 MB)
    uint16_t* q_ws = (uint16_t*)d_ws;
    uint16_t* k_ws = q_ws + 16859136;
    uint16_t* v_ws = k_ws + 16859136;
    float* bias_l = (float*)((char*)d_ws + 101154816);

    bias_pre<<<dim3((3 * NTOK * NTOK + 255) / 256), 256, 0, stream>>>(rpb, rel, bias_l);
    qkv_kernel<<<dim3(512 * 6), 256, 0, stream>>>(x, qkv_w, qkv_b, q_ws, k_ws, v_ws);
    attn_kernel<<<dim3(512 * 3), 512, 0, stream>>>(q_ws, k_ws, v_ws, mask, bias_l, out);
    proj_kernel<<<dim3(2744), 256, 0, stream>>>(proj_w, proj_b, out);
}